// Round 2
// baseline (455.909 us; speedup 1.0000x reference)
//
#include <hip/hip_runtime.h>

// EWMA: y[0]=x[0]; y[t] = a*x[t] + (1-a)*y[t-1], over (T=4096, 64, 256) fp32.
// Memory-bound serial scan. Time chunked (L=128) across blocks; each chunk
// reconstructs its carry with a W=32 warm-up (seed error ~0.7^32*~4 ~ 5e-5,
// threshold is 7.8e-3). float4/lane -> 16B coalesced. Grid 16x32 = 512 blocks
// = 2 blocks/CU = 2 waves/SIMD (2x round-0's TLP at identical redundant-read
// traffic: 31*32 ~= 15*64 warm-up step-reads).
// y is write-once/never-read -> nontemporal stores keep L2 for x.
// NOTE: __builtin_nontemporal_store needs a native clang vector type, not
// HIP_vector_type<float,4> -> use ext_vector_type(4).

#define A_COEF 0.3f
#define B_COEF 0.7f

typedef float vfloat4 __attribute__((ext_vector_type(4)));

constexpr int T  = 4096;
constexpr int C4 = 4096;   // (64*256)/4 float4 columns per time step
constexpr int L  = 128;    // time chunk length per block
constexpr int W  = 32;     // warm-up steps (0.7^32 ~= 1.1e-5 attenuation)

__global__ __launch_bounds__(256) void ewma_kernel(const vfloat4* __restrict__ x,
                                                   vfloat4* __restrict__ y) {
    const int c  = blockIdx.x * 256 + threadIdx.x;  // float4 column 0..4095
    const int k  = blockIdx.y;                      // time chunk
    const int t0 = k * L;

    vfloat4 carry;
    int t;
    if (k == 0) {
        carry = x[c];       // y[0] = x[0] exactly
        __builtin_nontemporal_store(carry, &y[c]);
        t = 1;
    } else {
        const int ts = t0 - W;
        carry = x[(size_t)ts * C4 + c];             // approx y[ts] ~= x[ts]
        #pragma unroll 8
        for (int tt = ts + 1; tt < t0; ++tt) {
            vfloat4 v = x[(size_t)tt * C4 + c];
            carry = A_COEF * v + B_COEF * carry;    // vector FMA
        }
        t = t0;
    }

    const int tend = t0 + L;
    #pragma unroll 8
    for (; t < tend; ++t) {
        const size_t idx = (size_t)t * C4 + c;
        vfloat4 v = x[idx];
        carry = A_COEF * v + B_COEF * carry;        // vector FMA
        __builtin_nontemporal_store(carry, &y[idx]);
    }
}

extern "C" void kernel_launch(void* const* d_in, const int* in_sizes, int n_in,
                              void* d_out, int out_size, void* d_ws, size_t ws_size,
                              hipStream_t stream) {
    const vfloat4* x = (const vfloat4*)d_in[0];
    vfloat4*       y = (vfloat4*)d_out;
    dim3 grid(C4 / 256, T / L);   // (16, 32)
    ewma_kernel<<<grid, 256, 0, stream>>>(x, y);
}

// Round 3
// 455.415 us; speedup vs baseline: 1.0011x; 1.0011x over previous
//
#include <hip/hip_runtime.h>

// EWMA: y[0]=x[0]; y[t] = a*x[t] + (1-a)*y[t-1], over (T=4096, 64, 256) fp32.
// Memory-bound serial scan. Time chunked (L=128) across blocks; each chunk
// reconstructs its carry with a W=32 warm-up (seed error ~0.7^32*~4 ~ 5e-5,
// threshold 7.8e-3). float4/lane coalesced. Grid 16x32 = 512 blocks.
//
// Round-2 structure: explicit 2-stage software pipeline (PF=8). Group g+1's
// loads are issued BEFORE group g's compute+stores, so in the vmcnt FIFO no
// store is ever older than a load we wait on -> store retire latency stays
// off the load critical path, and the load window is ~16 deep.
// Regular stores (NOT nontemporal): nt stores ack from HBM (~900cy) and
// gated the next load group in round 1 (171.8us, 2.53TB/s).
// k==0 is folded into the uniform pipeline: seeding carry=x[0] makes step 0
// compute 0.3*x0+0.7*x0 == x0 to 1 ulp (threshold is 7.8e-3).

#define A_COEF 0.3f
#define B_COEF 0.7f

typedef float vfloat4 __attribute__((ext_vector_type(4)));

constexpr int T  = 4096;
constexpr int C4 = 4096;   // (64*256)/4 float4 columns per time step
constexpr int L  = 128;    // time chunk length per block
constexpr int W  = 32;     // warm-up steps (0.7^32 ~= 1.1e-5 attenuation)
constexpr int PF = 8;      // pipeline group size (loads in flight >= 16)

__global__ __launch_bounds__(256) void ewma_kernel(const vfloat4* __restrict__ x,
                                                   vfloat4* __restrict__ y) {
    const int c  = blockIdx.x * 256 + threadIdx.x;  // float4 column 0..4095
    const int k  = blockIdx.y;                      // time chunk
    const int t0 = k * L;

    vfloat4 carry;
    if (k == 0) {
        carry = x[c];                   // step t=0 then yields x[0] (1 ulp)
    } else {
        const vfloat4* p = x + (size_t)(t0 - W) * C4 + c;
        carry = *p;                     // approx y[t0-W] ~= x[t0-W]
        #pragma unroll
        for (int i = 1; i < W; ++i) {
            p += C4;
            vfloat4 v = *p;
            carry = A_COEF * v + B_COEF * carry;
        }
    }

    // ---- software-pipelined main loop: L iterations in L/PF groups ----
    const vfloat4* pl = x + (size_t)t0 * C4 + c;
    vfloat4*       ps = y + (size_t)t0 * C4 + c;

    vfloat4 buf[PF];
    #pragma unroll
    for (int i = 0; i < PF; ++i) buf[i] = pl[(size_t)i * C4];
    pl += (size_t)PF * C4;

    #pragma unroll 1
    for (int g = 0; g < L / PF - 1; ++g) {
        vfloat4 nxt[PF];
        #pragma unroll
        for (int i = 0; i < PF; ++i) nxt[i] = pl[(size_t)i * C4];  // prefetch g+1
        pl += (size_t)PF * C4;

        #pragma unroll
        for (int i = 0; i < PF; ++i) {                             // compute+store g
            carry = A_COEF * buf[i] + B_COEF * carry;
            ps[(size_t)i * C4] = carry;
        }
        ps += (size_t)PF * C4;

        #pragma unroll
        for (int i = 0; i < PF; ++i) buf[i] = nxt[i];              // rotate regs
    }

    #pragma unroll
    for (int i = 0; i < PF; ++i) {                                 // epilogue group
        carry = A_COEF * buf[i] + B_COEF * carry;
        ps[(size_t)i * C4] = carry;
    }
}

extern "C" void kernel_launch(void* const* d_in, const int* in_sizes, int n_in,
                              void* d_out, int out_size, void* d_ws, size_t ws_size,
                              hipStream_t stream) {
    const vfloat4* x = (const vfloat4*)d_in[0];
    vfloat4*       y = (vfloat4*)d_out;
    dim3 grid(C4 / 256, T / L);   // (16, 32)
    ewma_kernel<<<grid, 256, 0, stream>>>(x, y);
}